// Round 12
// baseline (92.262 us; speedup 1.0000x reference)
//
#include <hip/hip_runtime.h>

// ReflexPolicy fused v12: 4 rows/thread (DS amortized over 2x rows), o-split
// blocks (512 blocks: 256 row-tiles x 2 o-halves, 2 blocks/CU, 8 waves/CU),
// v10 conflict-free o-packed LDS + stage-after-compute protocol verbatim,
// atomicAdd merge of the two o-half partials (R6-proven, deterministic).

#define TOBS 64
#define TACT 32
#define TLAT 25
#define TB   8192
#define BT   32         // rows per block
#define NCH  8          // 4-o chunks over this block's 32 o's
#define HSTR 68

#define DPP_ADD(x, ctrl) \
  ((x) + __builtin_bit_cast(float, __builtin_amdgcn_update_dpp( \
      0, __builtin_bit_cast(int, (x)), (ctrl), 0xF, 0xF, true)))

__device__ __forceinline__ float halfwave_sum(float x) {
    x = DPP_ADD(x, 0xB1);   // xor1
    x = DPP_ADD(x, 0x4E);   // xor2
    x = DPP_ADD(x, 0x141);  // row_half_mirror == xor4
    x = DPP_ADD(x, 0x140);  // row_mirror      == xor8
    int y = __builtin_amdgcn_ds_swizzle(__builtin_bit_cast(int, x), 0x401F); // xor16
    return x + __builtin_bit_cast(float, y);
}

__device__ __forceinline__ float sigmoidf_(float x) {
    return 1.0f / (1.0f + __expf(-x));
}

__global__ __launch_bounds__(256, 1)
void reflex_fused(const float* __restrict__ obs,
                  const float* __restrict__ sw1, const float* __restrict__ sb1,
                  const float* __restrict__ sw2, const float* __restrict__ sb2,
                  const float* __restrict__ sw3, const float* __restrict__ sb3,
                  const float* __restrict__ rw1, const float* __restrict__ rb1,
                  const float* __restrict__ rw2, const float* __restrict__ rb2,
                  const float* __restrict__ am,  float* __restrict__ out)
{
    __shared__ __align__(16) float obs_s[BT * HSTR];     // 8704 B
    __shared__ __align__(16) float lat_s[BT * 26];       // 3328 B
    __shared__ __align__(16) union {
        struct { float h1[BT * HSTR]; float h2[BT * HSTR]; } p1;      // 17408 B
        struct { float4 At4[2][25 * 32]; float4 W4[2][16 * 32]; } p2; // 41984 B
    } U;

    const int tid   = threadIdx.x;
    const int bid   = blockIdx.x;
    const int row0  = (bid >> 1) * BT;
    const int obase = (bid & 1) * 32;

    // ---------------- Phase 1: supervisor for 32 rows (weights from L2) ----------------
    {
        const int r = tid >> 3, f = tid & 7;
        *(float4*)&obs_s[r * HSTR + f * 8] =
            *(const float4*)&obs[(row0 + r) * TOBS + f * 8];
        *(float4*)&obs_s[r * HSTR + f * 8 + 4] =
            *(const float4*)&obs[(row0 + r) * TOBS + f * 8 + 4];
    }
    __syncthreads();

    {   // layer 1: two 16-row passes
        const int rr = tid >> 4, j0 = (tid & 15) * 4;
        #pragma unroll
        for (int rp = 0; rp < BT; rp += 16) {
            const int r = rp + rr;
            float4 acc = *(const float4*)&sb1[j0];
            #pragma unroll 8
            for (int k = 0; k < 64; ++k) {
                float x = obs_s[r * HSTR + k];
                const float4 w = *(const float4*)&sw1[k * 64 + j0];
                acc.x = fmaf(x, w.x, acc.x); acc.y = fmaf(x, w.y, acc.y);
                acc.z = fmaf(x, w.z, acc.z); acc.w = fmaf(x, w.w, acc.w);
            }
            *(float4*)&U.p1.h1[r * HSTR + j0] =
                make_float4(fmaxf(acc.x, 0.f), fmaxf(acc.y, 0.f),
                            fmaxf(acc.z, 0.f), fmaxf(acc.w, 0.f));
        }
    }
    __syncthreads();

    {   // layer 2
        const int rr = tid >> 4, j0 = (tid & 15) * 4;
        #pragma unroll
        for (int rp = 0; rp < BT; rp += 16) {
            const int r = rp + rr;
            float4 acc = *(const float4*)&sb2[j0];
            #pragma unroll 8
            for (int k = 0; k < 64; ++k) {
                float x = U.p1.h1[r * HSTR + k];
                const float4 w = *(const float4*)&sw2[k * 64 + j0];
                acc.x = fmaf(x, w.x, acc.x); acc.y = fmaf(x, w.y, acc.y);
                acc.z = fmaf(x, w.z, acc.z); acc.w = fmaf(x, w.w, acc.w);
            }
            *(float4*)&U.p1.h2[r * HSTR + j0] =
                make_float4(fmaxf(acc.x, 0.f), fmaxf(acc.y, 0.f),
                            fmaxf(acc.z, 0.f), fmaxf(acc.w, 0.f));
        }
    }
    __syncthreads();

    {   // layer 3 -> lat_s
        const int rr = tid >> 4, q = tid & 15;
        if (q < 13) {
            const int j = q * 2;
            #pragma unroll
            for (int rp = 0; rp < BT; rp += 16) {
                const int r = rp + rr;
                float a0 = sb3[j];
                float a1 = (j + 1 < TLAT) ? sb3[j + 1] : 0.f;
                #pragma unroll 8
                for (int k = 0; k < 64; ++k) {
                    float x = U.p1.h2[r * HSTR + k];
                    a0 = fmaf(x, sw3[k * TLAT + j], a0);
                    if (j + 1 < TLAT) a1 = fmaf(x, sw3[k * TLAT + j + 1], a1);
                }
                lat_s[r * 26 + j] = sigmoidf_(a0);
                if (j + 1 < TLAT) lat_s[r * 26 + j + 1] = sigmoidf_(a1);
            }
        }
    }
    __syncthreads();   // lat_s ready; h1/h2 (union) dead

    // ---------------- Phase 2: 4 rows/thread over this block's 32 o's ----------------
    const int a  = tid & 31;
    const int g  = tid >> 5;        // 0..7
    const int r0 = g * 4;           // rows r0..r0+3

    float lat[4][25];
    #pragma unroll
    for (int rr = 0; rr < 4; ++rr)
        #pragma unroll
        for (int l = 0; l < TLAT; ++l)
            lat[rr][l] = lat_s[(r0 + rr) * 26 + l];

    // W word k source for reflex net n (flat o*32+a):
    auto wload = [&](int k, int n) -> float {
        if (k < 5)  return rw1[n * 5 + k];
        if (k < 10) return rb1[n * 5 + (k - 5)];
        if (k < 15) return rw2[n * 5 + (k - 10)];
        return rb2[n];
    };

    // Stage chunk c into buffer b (v10 verbatim, cb generalized to the o-half).
    auto stage = [&](int c, int b) {
        const int cb = obase * 32 + c * 128;
        {
            int e = tid, l = e >> 5, a_ = e & 31;
            const float* gp = am + l * 2048 + cb + a_;
            float4 v; v.x = gp[0]; v.y = gp[32]; v.z = gp[64]; v.w = gp[96];
            U.p2.At4[b][e] = v;

            e = tid + 256; l = e >> 5; a_ = e & 31;
            const float* g2 = am + l * 2048 + cb + a_;
            float4 v2; v2.x = g2[0]; v2.y = g2[32]; v2.z = g2[64]; v2.w = g2[96];
            U.p2.At4[b][e] = v2;

            e = tid + 512; l = e >> 5; a_ = e & 31;
            const float* g3 = am + l * 2048 + cb + a_;
            float4 v3; v3.x = g3[0]; v3.y = g3[32]; v3.z = g3[64]; v3.w = g3[96];
            U.p2.At4[b][e] = v3;

            if (tid < 32) {
                const float* g4 = am + 24 * 2048 + cb + tid;
                float4 v4; v4.x = g4[0]; v4.y = g4[32]; v4.z = g4[64]; v4.w = g4[96];
                U.p2.At4[b][tid + 768] = v4;
            }
        }
        {
            int k = tid >> 5, a_ = tid & 31;
            int n0 = cb + a_;
            float4 w;
            w.x = wload(k, n0);      w.y = wload(k, n0 + 32);
            w.z = wload(k, n0 + 64); w.w = wload(k, n0 + 96);
            U.p2.W4[b][tid] = w;

            k += 8;
            float4 w2;
            w2.x = wload(k, n0);      w2.y = wload(k, n0 + 32);
            w2.z = wload(k, n0 + 64); w2.w = wload(k, n0 + 96);
            U.p2.W4[b][tid + 256] = w2;
        }
    };

    float acc[4] = {0.f, 0.f, 0.f, 0.f};

    stage(0, 0);
    __syncthreads();

    for (int c = 0; c < NCH; ++c) {
        const float4* A4 = U.p2.At4[c & 1];
        const float4* Wb = U.p2.W4[c & 1];

        // ---- dot over l: 4 rows x 4 o's = 16 independent chains, 25 b128 reads
        float lg[4][4] = {{0.f,0.f,0.f,0.f},{0.f,0.f,0.f,0.f},
                          {0.f,0.f,0.f,0.f},{0.f,0.f,0.f,0.f}};
        #pragma unroll
        for (int l = 0; l < TLAT; ++l) {
            const float4 q = A4[l * 32 + a];
            #pragma unroll
            for (int rr = 0; rr < 4; ++rr) {
                lg[rr][0] = fmaf(q.x, lat[rr][l], lg[rr][0]);
                lg[rr][1] = fmaf(q.y, lat[rr][l], lg[rr][1]);
                lg[rr][2] = fmaf(q.z, lat[rr][l], lg[rr][2]);
                lg[rr][3] = fmaf(q.w, lat[rr][l], lg[rr][3]);
            }
        }

        // ---- softmax over a: 16 independent chains
        float p[4][4];
        #pragma unroll
        for (int rr = 0; rr < 4; ++rr) {
            #pragma unroll
            for (int oo = 0; oo < 4; ++oo) {
                float e = __expf(lg[rr][oo]);
                p[rr][oo] = e * __builtin_amdgcn_rcpf(halfwave_sum(e));
            }
        }

        // ---- reflex MLPs: 4 rows x 4 o's
        const int ob = obase + c * 4;
        float4 xv0 = *(const float4*)&obs_s[(r0 + 0) * HSTR + ob];
        float4 xv1 = *(const float4*)&obs_s[(r0 + 1) * HSTR + ob];
        float4 xv2 = *(const float4*)&obs_s[(r0 + 2) * HSTR + ob];
        float4 xv3 = *(const float4*)&obs_s[(r0 + 3) * HSTR + ob];

        const float4 B2 = Wb[15 * 32 + a];
        float q_[4][4];
        #pragma unroll
        for (int rr = 0; rr < 4; ++rr) {
            q_[rr][0] = B2.x; q_[rr][1] = B2.y; q_[rr][2] = B2.z; q_[rr][3] = B2.w;
        }
        #pragma unroll
        for (int h = 0; h < 5; ++h) {
            const float4 w1v = Wb[h * 32 + a];
            const float4 b1v = Wb[(5 + h) * 32 + a];
            const float4 w2v = Wb[(10 + h) * 32 + a];
            q_[0][0] = fmaf(fmaxf(fmaf(xv0.x, w1v.x, b1v.x), 0.f), w2v.x, q_[0][0]);
            q_[0][1] = fmaf(fmaxf(fmaf(xv0.y, w1v.y, b1v.y), 0.f), w2v.y, q_[0][1]);
            q_[0][2] = fmaf(fmaxf(fmaf(xv0.z, w1v.z, b1v.z), 0.f), w2v.z, q_[0][2]);
            q_[0][3] = fmaf(fmaxf(fmaf(xv0.w, w1v.w, b1v.w), 0.f), w2v.w, q_[0][3]);
            q_[1][0] = fmaf(fmaxf(fmaf(xv1.x, w1v.x, b1v.x), 0.f), w2v.x, q_[1][0]);
            q_[1][1] = fmaf(fmaxf(fmaf(xv1.y, w1v.y, b1v.y), 0.f), w2v.y, q_[1][1]);
            q_[1][2] = fmaf(fmaxf(fmaf(xv1.z, w1v.z, b1v.z), 0.f), w2v.z, q_[1][2]);
            q_[1][3] = fmaf(fmaxf(fmaf(xv1.w, w1v.w, b1v.w), 0.f), w2v.w, q_[1][3]);
            q_[2][0] = fmaf(fmaxf(fmaf(xv2.x, w1v.x, b1v.x), 0.f), w2v.x, q_[2][0]);
            q_[2][1] = fmaf(fmaxf(fmaf(xv2.y, w1v.y, b1v.y), 0.f), w2v.y, q_[2][1]);
            q_[2][2] = fmaf(fmaxf(fmaf(xv2.z, w1v.z, b1v.z), 0.f), w2v.z, q_[2][2]);
            q_[2][3] = fmaf(fmaxf(fmaf(xv2.w, w1v.w, b1v.w), 0.f), w2v.w, q_[2][3]);
            q_[3][0] = fmaf(fmaxf(fmaf(xv3.x, w1v.x, b1v.x), 0.f), w2v.x, q_[3][0]);
            q_[3][1] = fmaf(fmaxf(fmaf(xv3.y, w1v.y, b1v.y), 0.f), w2v.y, q_[3][1]);
            q_[3][2] = fmaf(fmaxf(fmaf(xv3.z, w1v.z, b1v.z), 0.f), w2v.z, q_[3][2]);
            q_[3][3] = fmaf(fmaxf(fmaf(xv3.w, w1v.w, b1v.w), 0.f), w2v.w, q_[3][3]);
        }

        #pragma unroll
        for (int rr = 0; rr < 4; ++rr) {
            acc[rr] = fmaf(q_[rr][0], p[rr][0], acc[rr]);
            acc[rr] = fmaf(q_[rr][1], p[rr][1], acc[rr]);
            acc[rr] = fmaf(q_[rr][2], p[rr][2], acc[rr]);
            acc[rr] = fmaf(q_[rr][3], p[rr][3], acc[rr]);
        }

        if (c + 1 < NCH) stage(c + 1, (c + 1) & 1);  // proven protocol: stage after compute
        __syncthreads();
    }

    // merge the two o-half blocks (2 commutative fp32 adds -> deterministic)
    #pragma unroll
    for (int rr = 0; rr < 4; ++rr)
        unsafeAtomicAdd(&out[(row0 + r0 + rr) * TACT + a], acc[rr]);
}

extern "C" void kernel_launch(void* const* d_in, const int* in_sizes, int n_in,
                              void* d_out, int out_size, void* d_ws, size_t ws_size,
                              hipStream_t stream) {
    const float* obs = (const float*)d_in[0];
    const float* sw1 = (const float*)d_in[1];
    const float* sb1 = (const float*)d_in[2];
    const float* sw2 = (const float*)d_in[3];
    const float* sb2 = (const float*)d_in[4];
    const float* sw3 = (const float*)d_in[5];
    const float* sb3 = (const float*)d_in[6];
    const float* rw1 = (const float*)d_in[7];
    const float* rb1 = (const float*)d_in[8];
    const float* rw2 = (const float*)d_in[9];
    const float* rb2 = (const float*)d_in[10];
    const float* am  = (const float*)d_in[11];
    float* out = (float*)d_out;

    hipMemsetAsync(out, 0, (size_t)out_size * sizeof(float), stream);
    reflex_fused<<<(TB / BT) * 2, 256, 0, stream>>>(obs, sw1, sb1, sw2, sb2, sw3, sb3,
                                                    rw1, rb1, rw2, rb2, am, out);
}

// Round 13
// 65.254 us; speedup vs baseline: 1.4139x; 1.4139x over previous
//
#include <hip/hip_runtime.h>

// ReflexPolicy fused v13: LDS-free phase 2. Latents -> SGPR via readfirstlane
// (block-uniform data), A/W stream L2->regs with coalesced float4 loads
// (am[l*2048 + lane*4] is contiguous across the wave). Softmax in 8-lane
// groups via in-reg sum4 + 3 DPP stages. o-reduction once per pass
// (xor8/xor16 swizzle + shfl_xor 32). No barriers in phase 2.

#define TOBS 64
#define TACT 32
#define TLAT 25
#define TB   8192
#define BT   16
#define HSTR 68

#define DPP_ADD(x, ctrl) \
  ((x) + __builtin_bit_cast(float, __builtin_amdgcn_update_dpp( \
      0, __builtin_bit_cast(int, (x)), (ctrl), 0xF, 0xF, true)))

__device__ __forceinline__ float sigmoidf_(float x) {
    return 1.0f / (1.0f + __expf(-x));
}

__device__ __forceinline__ float osum_(float v) {
    int t = __builtin_amdgcn_ds_swizzle(__builtin_bit_cast(int, v), 0x201F); // xor8
    v += __builtin_bit_cast(float, t);
    t = __builtin_amdgcn_ds_swizzle(__builtin_bit_cast(int, v), 0x401F);     // xor16
    v += __builtin_bit_cast(float, t);
    v += __shfl_xor(v, 32);                                                  // xor32
    return v;
}

__device__ __forceinline__ float sload_(const float* lds_p) {
    return __builtin_bit_cast(float, (int)__builtin_amdgcn_readfirstlane(
        __builtin_bit_cast(int, *lds_p)));
}

__global__ __launch_bounds__(256, 1)
void reflex_fused(const float* __restrict__ obs,
                  const float* __restrict__ sw1, const float* __restrict__ sb1,
                  const float* __restrict__ sw2, const float* __restrict__ sb2,
                  const float* __restrict__ sw3, const float* __restrict__ sb3,
                  const float* __restrict__ rw1, const float* __restrict__ rb1,
                  const float* __restrict__ rw2, const float* __restrict__ rb2,
                  const float* __restrict__ am,  float* __restrict__ out)
{
    __shared__ __align__(16) float obs_s[BT * HSTR];
    __shared__ __align__(16) float h1_s[BT * HSTR];
    __shared__ __align__(16) float h2_s[BT * HSTR];
    __shared__ __align__(16) float lat_s[BT * 26];

    const int tid  = threadIdx.x;
    const int row0 = blockIdx.x * BT;

    // ---------------- Phase 1: supervisor (v5-proven, weights from L2) ----------------
    {
        const int r = tid >> 4, f = tid & 15;
        *(float4*)&obs_s[r * HSTR + f * 4] =
            *(const float4*)&obs[(row0 + r) * TOBS + f * 4];
    }
    __syncthreads();

    {   // layer 1
        const int r = tid >> 4, j0 = (tid & 15) * 4;
        float4 acc = *(const float4*)&sb1[j0];
        #pragma unroll 8
        for (int k = 0; k < 64; ++k) {
            float x = obs_s[r * HSTR + k];
            const float4 w = *(const float4*)&sw1[k * 64 + j0];
            acc.x = fmaf(x, w.x, acc.x); acc.y = fmaf(x, w.y, acc.y);
            acc.z = fmaf(x, w.z, acc.z); acc.w = fmaf(x, w.w, acc.w);
        }
        *(float4*)&h1_s[r * HSTR + j0] =
            make_float4(fmaxf(acc.x, 0.f), fmaxf(acc.y, 0.f),
                        fmaxf(acc.z, 0.f), fmaxf(acc.w, 0.f));
    }
    __syncthreads();

    {   // layer 2
        const int r = tid >> 4, j0 = (tid & 15) * 4;
        float4 acc = *(const float4*)&sb2[j0];
        #pragma unroll 8
        for (int k = 0; k < 64; ++k) {
            float x = h1_s[r * HSTR + k];
            const float4 w = *(const float4*)&sw2[k * 64 + j0];
            acc.x = fmaf(x, w.x, acc.x); acc.y = fmaf(x, w.y, acc.y);
            acc.z = fmaf(x, w.z, acc.z); acc.w = fmaf(x, w.w, acc.w);
        }
        *(float4*)&h2_s[r * HSTR + j0] =
            make_float4(fmaxf(acc.x, 0.f), fmaxf(acc.y, 0.f),
                        fmaxf(acc.z, 0.f), fmaxf(acc.w, 0.f));
    }
    __syncthreads();

    {   // layer 3 -> lat_s
        const int r = tid >> 4, q = tid & 15;
        if (q < 13) {
            const int j = q * 2;
            float a0 = sb3[j];
            float a1 = (j + 1 < TLAT) ? sb3[j + 1] : 0.f;
            #pragma unroll 8
            for (int k = 0; k < 64; ++k) {
                float x = h2_s[r * HSTR + k];
                a0 = fmaf(x, sw3[k * TLAT + j], a0);
                if (j + 1 < TLAT) a1 = fmaf(x, sw3[k * TLAT + j + 1], a1);
            }
            lat_s[r * 26 + j] = sigmoidf_(a0);
            if (j + 1 < TLAT) lat_s[r * 26 + j + 1] = sigmoidf_(a1);
        }
    }
    __syncthreads();   // lat_s ready; phase 2 is barrier-free

    // ---------------- Phase 2: LDS-free streaming ----------------
    const int lane  = tid & 63;
    const int wid   = tid >> 6;       // wave 0..3 owns rows wid*4 .. wid*4+3
    const int o_sub = lane >> 3;      // 0..7
    const int aq    = lane & 7;       // a-quad 0..7
    const int colb  = lane * 4;       // column offset within an oc block of 256

    #pragma unroll
    for (int pass = 0; pass < 2; ++pass) {
        const int rA = wid * 4 + pass * 2;     // local row A
        const int rB = rA + 1;                 // local row B

        // latents for 2 rows -> uniform (SGPR) regs
        float sA[TLAT], sB[TLAT];
        #pragma unroll
        for (int l = 0; l < TLAT; ++l) {
            sA[l] = sload_(&lat_s[rA * 26 + l]);
            sB[l] = sload_(&lat_s[rB * 26 + l]);
        }

        float accA[4] = {0.f, 0.f, 0.f, 0.f};
        float accB[4] = {0.f, 0.f, 0.f, 0.f};

        for (int oc = 0; oc < 8; ++oc) {
            const float* Ab = am + oc * 256 + colb;

            // ---- logits: 25 coalesced float4 loads from L2, 8 fma chains
            float4 La = make_float4(0.f, 0.f, 0.f, 0.f);
            float4 Lb = make_float4(0.f, 0.f, 0.f, 0.f);
            #pragma unroll
            for (int l = 0; l < TLAT; ++l) {
                const float4 Av = *(const float4*)(Ab + l * 2048);
                La.x = fmaf(Av.x, sA[l], La.x); Lb.x = fmaf(Av.x, sB[l], Lb.x);
                La.y = fmaf(Av.y, sA[l], La.y); Lb.y = fmaf(Av.y, sB[l], Lb.y);
                La.z = fmaf(Av.z, sA[l], La.z); Lb.z = fmaf(Av.z, sB[l], Lb.z);
                La.w = fmaf(Av.w, sA[l], La.w); Lb.w = fmaf(Av.w, sB[l], Lb.w);
            }

            // ---- issue W loads early (latency hides under softmax)
            const int wb = (oc * 256 + colb) * 5;     // 20 floats per thread
            const float4 W1a = *(const float4*)&rw1[wb];
            const float4 W1b = *(const float4*)&rw1[wb + 4];
            const float4 W1c = *(const float4*)&rw1[wb + 8];
            const float4 W1d = *(const float4*)&rw1[wb + 12];
            const float4 W1e = *(const float4*)&rw1[wb + 16];
            const float4 B1a = *(const float4*)&rb1[wb];
            const float4 B1b = *(const float4*)&rb1[wb + 4];
            const float4 B1c = *(const float4*)&rb1[wb + 8];
            const float4 B1d = *(const float4*)&rb1[wb + 12];
            const float4 B1e = *(const float4*)&rb1[wb + 16];
            const float4 W2a = *(const float4*)&rw2[wb];
            const float4 W2b = *(const float4*)&rw2[wb + 4];
            const float4 W2c = *(const float4*)&rw2[wb + 8];
            const float4 W2d = *(const float4*)&rw2[wb + 12];
            const float4 W2e = *(const float4*)&rw2[wb + 16];
            const float4 B2v = *(const float4*)&rb2[oc * 256 + colb];

            // ---- softmax over a: in-reg sum4 + DPP xor1/xor2/(xor4 via mirror)
            float eA0 = __expf(La.x), eA1 = __expf(La.y), eA2 = __expf(La.z), eA3 = __expf(La.w);
            float eB0 = __expf(Lb.x), eB1 = __expf(Lb.y), eB2 = __expf(Lb.z), eB3 = __expf(Lb.w);
            float dA = (eA0 + eA1) + (eA2 + eA3);
            float dB = (eB0 + eB1) + (eB2 + eB3);
            dA = DPP_ADD(dA, 0xB1); dA = DPP_ADD(dA, 0x4E); dA = DPP_ADD(dA, 0x141);
            dB = DPP_ADD(dB, 0xB1); dB = DPP_ADD(dB, 0x4E); dB = DPP_ADD(dB, 0x141);
            const float rcA = __builtin_amdgcn_rcpf(dA);
            const float rcB = __builtin_amdgcn_rcpf(dB);
            float pA[4] = {eA0 * rcA, eA1 * rcA, eA2 * rcA, eA3 * rcA};
            float pB[4] = {eB0 * rcB, eB1 * rcB, eB2 * rcB, eB3 * rcB};

            // ---- W element arrays (static indices only -> registers)
            float w1e[20], b1e[20], w2e[20], b2e[4];
            w1e[0]=W1a.x; w1e[1]=W1a.y; w1e[2]=W1a.z; w1e[3]=W1a.w;
            w1e[4]=W1b.x; w1e[5]=W1b.y; w1e[6]=W1b.z; w1e[7]=W1b.w;
            w1e[8]=W1c.x; w1e[9]=W1c.y; w1e[10]=W1c.z; w1e[11]=W1c.w;
            w1e[12]=W1d.x; w1e[13]=W1d.y; w1e[14]=W1d.z; w1e[15]=W1d.w;
            w1e[16]=W1e.x; w1e[17]=W1e.y; w1e[18]=W1e.z; w1e[19]=W1e.w;
            b1e[0]=B1a.x; b1e[1]=B1a.y; b1e[2]=B1a.z; b1e[3]=B1a.w;
            b1e[4]=B1b.x; b1e[5]=B1b.y; b1e[6]=B1b.z; b1e[7]=B1b.w;
            b1e[8]=B1c.x; b1e[9]=B1c.y; b1e[10]=B1c.z; b1e[11]=B1c.w;
            b1e[12]=B1d.x; b1e[13]=B1d.y; b1e[14]=B1d.z; b1e[15]=B1d.w;
            b1e[16]=B1e.x; b1e[17]=B1e.y; b1e[18]=B1e.z; b1e[19]=B1e.w;
            w2e[0]=W2a.x; w2e[1]=W2a.y; w2e[2]=W2a.z; w2e[3]=W2a.w;
            w2e[4]=W2b.x; w2e[5]=W2b.y; w2e[6]=W2b.z; w2e[7]=W2b.w;
            w2e[8]=W2c.x; w2e[9]=W2c.y; w2e[10]=W2c.z; w2e[11]=W2c.w;
            w2e[12]=W2d.x; w2e[13]=W2d.y; w2e[14]=W2d.z; w2e[15]=W2d.w;
            w2e[16]=W2e.x; w2e[17]=W2e.y; w2e[18]=W2e.z; w2e[19]=W2e.w;
            b2e[0]=B2v.x; b2e[1]=B2v.y; b2e[2]=B2v.z; b2e[3]=B2v.w;

            // ---- reflex MLPs (x from LDS, broadcast within 8-lane group)
            const int o = oc * 8 + o_sub;
            const float xA = obs_s[rA * HSTR + o];
            const float xB = obs_s[rB * HSTR + o];

            #pragma unroll
            for (int j = 0; j < 4; ++j) {
                float roA = b2e[j], roB = b2e[j];
                #pragma unroll
                for (int h = 0; h < 5; ++h) {
                    const float w1 = w1e[j * 5 + h];
                    const float b1 = b1e[j * 5 + h];
                    const float w2 = w2e[j * 5 + h];
                    roA = fmaf(fmaxf(fmaf(xA, w1, b1), 0.f), w2, roA);
                    roB = fmaf(fmaxf(fmaf(xB, w1, b1), 0.f), w2, roB);
                }
                accA[j] = fmaf(roA, pA[j], accA[j]);
                accB[j] = fmaf(roB, pB[j], accB[j]);
            }
        }

        // ---- reduce over the 8 o_sub lanes, then store (lanes 0..7 only)
        #pragma unroll
        for (int j = 0; j < 4; ++j) {
            accA[j] = osum_(accA[j]);
            accB[j] = osum_(accB[j]);
        }
        if (lane < 8) {
            *(float4*)&out[(row0 + rA) * TACT + aq * 4] =
                make_float4(accA[0], accA[1], accA[2], accA[3]);
            *(float4*)&out[(row0 + rB) * TACT + aq * 4] =
                make_float4(accB[0], accB[1], accB[2], accB[3]);
        }
    }
}

extern "C" void kernel_launch(void* const* d_in, const int* in_sizes, int n_in,
                              void* d_out, int out_size, void* d_ws, size_t ws_size,
                              hipStream_t stream) {
    const float* obs = (const float*)d_in[0];
    const float* sw1 = (const float*)d_in[1];
    const float* sb1 = (const float*)d_in[2];
    const float* sw2 = (const float*)d_in[3];
    const float* sb2 = (const float*)d_in[4];
    const float* sw3 = (const float*)d_in[5];
    const float* sb3 = (const float*)d_in[6];
    const float* rw1 = (const float*)d_in[7];
    const float* rb1 = (const float*)d_in[8];
    const float* rw2 = (const float*)d_in[9];
    const float* rb2 = (const float*)d_in[10];
    const float* am  = (const float*)d_in[11];
    float* out = (float*)d_out;

    reflex_fused<<<TB / BT, 256, 0, stream>>>(obs, sw1, sb1, sw2, sb2, sw3, sb3,
                                              rw1, rb1, rw2, rb2, am, out);
}